// Round 9
// baseline (430.653 us; speedup 1.0000x reference)
//
#include <hip/hip_runtime.h>
#include <hip/hip_bf16.h>

#define IN_DIM    1024
#define HEAD_DIM  64
#define NUM_HEADS 16
#define SEQ       4096

// 1/sqrt(64) * log2(e), folded into Q (fp32, pre-bf16-cast). Softmax via exp2.
#define QSCALE 0.18033688011112042f

typedef __bf16 bf16;
typedef __attribute__((ext_vector_type(4))) __bf16 bf16x4;
typedef __attribute__((ext_vector_type(8))) __bf16 bf16x8;
typedef __attribute__((ext_vector_type(4))) float floatx4;
typedef __attribute__((ext_vector_type(4))) short s16x4;

__device__ __forceinline__ void async16(bf16* lds, const bf16* g) {
    __builtin_amdgcn_global_load_lds(
        (const __attribute__((address_space(1))) unsigned int*)g,
        (__attribute__((address_space(3))) unsigned int*)lds, 16, 0, 0);
}

// K=16 MFMA: D = A(4xbf16) * B(4xbf16) + C.  A[m=l16][k=quad*4+j],
// B[k=quad*4+j][n=l16], C/D[row=quad*4+r][col=l16].
__device__ __forceinline__ floatx4 mfma16(bf16x4 a, bf16x4 b, floatx4 c) {
#if __has_builtin(__builtin_amdgcn_mfma_f32_16x16x16bf16_1k)
    union U { bf16x4 h; s16x4 s; };
    U ua, ub; ua.h = a; ub.h = b;
    return __builtin_amdgcn_mfma_f32_16x16x16bf16_1k(ua.s, ub.s, c, 0, 0, 0);
#else
    // zero-pad to K=32: real data sits at k=8q+j (j<4) in BOTH operands -> exact
    bf16 z = (bf16)0.f;
    bf16x8 a8 = {a[0], a[1], a[2], a[3], z, z, z, z};
    bf16x8 b8 = {b[0], b[1], b[2], b[3], z, z, z, z};
    return __builtin_amdgcn_mfma_f32_16x16x32_bf16(a8, b8, c, 0, 0, 0);
#endif
}

// ---------------------------------------------------------------------------
// ws layout: Qb@0 (8M) | Kb@8M | Vt@16M | hb@24M (8M) | Wt@32M (6M)
// split mode: Op (TS x 16.78M fp32 partials) overlays hb/Wt @24M, Lp after.
// ---------------------------------------------------------------------------

__global__ void mha_conv_h(const float* __restrict__ h, bf16* __restrict__ hb) {
    int i = blockIdx.x * blockDim.x + threadIdx.x;
    float4 v = ((const float4*)h)[i];
    bf16x4 r;
    r[0] = (bf16)v.x; r[1] = (bf16)v.y; r[2] = (bf16)v.z; r[3] = (bf16)v.w;
    ((bf16x4*)hb)[i] = r;
}

__global__ void mha_conv_wt(const float* __restrict__ Wq, const float* __restrict__ Wk,
                            const float* __restrict__ Wv, bf16* __restrict__ Wt) {
    __shared__ bf16 tile[64][65];
    const int mat = blockIdx.z;
    const float* W = (mat == 0) ? Wq : (mat == 1) ? Wk : Wv;
    const int k0 = blockIdx.y * 64, n0 = blockIdx.x * 64;
    const int tn = threadIdx.x & 63, tq = threadIdx.x >> 6;
#pragma unroll
    for (int i = 0; i < 16; ++i) {
        int kk = tq + i * 4;
        tile[kk][tn] = (bf16)W[(size_t)(k0 + kk) * 1024 + n0 + tn];
    }
    __syncthreads();
#pragma unroll
    for (int i = 0; i < 16; ++i) {
        int nn = tq + i * 4;
        Wt[((size_t)mat << 20) + (size_t)(n0 + nn) * 1024 + k0 + tn] = tile[tn][nn];
    }
}

// ---------------------------------------------------------------------------
// QKV GEMM: 128x128 tile, BK=32, global_load_lds staging, XOR swizzle.
// mat==2 (V): operands swapped -> V^T output, coalesced Vt stores.
// ---------------------------------------------------------------------------
__launch_bounds__(256)
__global__ void mha_qkv_gemm(const bf16* __restrict__ hb, const bf16* __restrict__ Wt,
                             const float* __restrict__ bq, const float* __restrict__ bk,
                             const float* __restrict__ bv,
                             bf16* __restrict__ Qb, bf16* __restrict__ Kb,
                             bf16* __restrict__ Vt) {
    __shared__ __align__(16) bf16 As[128 * 32];
    __shared__ __align__(16) bf16 Bs[128 * 32];

    const int lane = threadIdx.x & 63;
    const int wave = threadIdx.x >> 6;
    const int l16  = lane & 15;
    const int quad = lane >> 4;
    const int wm   = wave & 1;
    const int wn   = wave >> 1;

    const int m0  = blockIdx.x * 128;
    const int n0  = blockIdx.y * 128;
    const int mat = n0 >> 10;
    const int nc0 = n0 & 1023;

    const bf16* Wp = Wt + ((size_t)mat << 20);

    floatx4 acc[4][4] = {};
    const int swz = (l16 >> 1) & 3;

    int g0 = wave * 128 + lane, g1 = g0 + 64;
    int row0 = g0 >> 2, gc0 = (g0 & 3) ^ ((row0 >> 1) & 3);
    int row1 = g1 >> 2, gc1 = (g1 & 3) ^ ((row1 >> 1) & 3);
    bf16* la0 = As + (size_t)(wave * 128) * 8;
    bf16* la1 = As + (size_t)(wave * 128 + 64) * 8;
    bf16* lb0 = Bs + (size_t)(wave * 128) * 8;
    bf16* lb1 = Bs + (size_t)(wave * 128 + 64) * 8;

    if (mat != 2) {
        for (int k0 = 0; k0 < IN_DIM; k0 += 32) {
            async16(la0, hb + (size_t)(m0 + row0) * IN_DIM + k0 + gc0 * 8);
            async16(la1, hb + (size_t)(m0 + row1) * IN_DIM + k0 + gc1 * 8);
            async16(lb0, Wp + (size_t)(nc0 + row0) * IN_DIM + k0 + gc0 * 8);
            async16(lb1, Wp + (size_t)(nc0 + row1) * IN_DIM + k0 + gc1 * 8);
            __syncthreads();
            bf16x8 af[4], bf[4];
#pragma unroll
            for (int mt = 0; mt < 4; ++mt)
                af[mt] = *(const bf16x8*)(As + (size_t)(wm * 64 + mt * 16 + l16) * 32
                                          + ((quad ^ swz) * 8));
#pragma unroll
            for (int nt = 0; nt < 4; ++nt)
                bf[nt] = *(const bf16x8*)(Bs + (size_t)(wn * 64 + nt * 16 + l16) * 32
                                          + ((quad ^ swz) * 8));
#pragma unroll
            for (int mt = 0; mt < 4; ++mt)
#pragma unroll
                for (int nt = 0; nt < 4; ++nt)
                    acc[mt][nt] = __builtin_amdgcn_mfma_f32_16x16x32_bf16(af[mt], bf[nt],
                                                                          acc[mt][nt], 0, 0, 0);
            __syncthreads();
        }
        const float* bias = (mat == 0) ? bq : bk;
#pragma unroll
        for (int nt = 0; nt < 4; ++nt) {
            int nc = nc0 + wn * 64 + nt * 16 + l16;
            float bb = bias[nc];
            int head = nc >> 6, d = nc & 63;
#pragma unroll
            for (int mt = 0; mt < 4; ++mt)
#pragma unroll
                for (int r = 0; r < 4; ++r) {
                    int srow = m0 + wm * 64 + mt * 16 + quad * 4 + r;
                    float v = acc[mt][nt][r] + bb;
                    if (mat == 0)
                        Qb[((size_t)head * SEQ + srow) * HEAD_DIM + d] = (bf16)(v * QSCALE);
                    else
                        Kb[((size_t)head * SEQ + srow) * HEAD_DIM + d] = (bf16)v;
                }
        }
    } else {
        for (int k0 = 0; k0 < IN_DIM; k0 += 32) {
            async16(la0, hb + (size_t)(m0 + row0) * IN_DIM + k0 + gc0 * 8);
            async16(la1, hb + (size_t)(m0 + row1) * IN_DIM + k0 + gc1 * 8);
            async16(lb0, Wp + (size_t)(nc0 + row0) * IN_DIM + k0 + gc0 * 8);
            async16(lb1, Wp + (size_t)(nc0 + row1) * IN_DIM + k0 + gc1 * 8);
            __syncthreads();
            bf16x8 af[4], bf[4];
#pragma unroll
            for (int mt = 0; mt < 4; ++mt)
                af[mt] = *(const bf16x8*)(As + (size_t)(wm * 64 + mt * 16 + l16) * 32
                                          + ((quad ^ swz) * 8));
#pragma unroll
            for (int nt = 0; nt < 4; ++nt)
                bf[nt] = *(const bf16x8*)(Bs + (size_t)(wn * 64 + nt * 16 + l16) * 32
                                          + ((quad ^ swz) * 8));
#pragma unroll
            for (int mt = 0; mt < 4; ++mt)
#pragma unroll
                for (int nt = 0; nt < 4; ++nt)
                    acc[mt][nt] = __builtin_amdgcn_mfma_f32_16x16x32_bf16(bf[nt], af[mt],
                                                                          acc[mt][nt], 0, 0, 0);
            __syncthreads();
        }
#pragma unroll
        for (int nt = 0; nt < 4; ++nt)
#pragma unroll
            for (int r = 0; r < 4; ++r) {
                int n = nc0 + wn * 64 + nt * 16 + quad * 4 + r;
                float bb = bv[n];
                int head = n >> 6, d = n & 63;
#pragma unroll
                for (int mt = 0; mt < 4; ++mt) {
                    int s = m0 + wm * 64 + mt * 16 + l16;
                    Vt[((size_t)head * 64 + d) * SEQ + s] = (bf16)(acc[mt][nt][r] + bb);
                }
            }
    }
}

// ---------------------------------------------------------------------------
// Attention: 256 threads = 4 waves x 64 q-rows. NO P LDS round-trip:
// S^T C-frag == B-operand frag of 16x16x16 MFMA, so PV is computed as
// O^T[d][m] += V^T(A) x P^T(B) straight from registers. Rowsums are fp32
// adds folded into the exp loop + 2 cross-quad shuffles at the end.
// K/V double-buffered via global_load_lds (32 KB LDS total).
// TS-way t-split across grid.z with fp32 additive partials.
// ---------------------------------------------------------------------------
template<int TS>
__launch_bounds__(256, 3)
__global__ void mha_attn(const bf16* __restrict__ Qb, const bf16* __restrict__ Kb,
                         const bf16* __restrict__ Vt, float* __restrict__ Op,
                         float* __restrict__ Lp, float* __restrict__ out) {
    __shared__ __align__(16) bf16 Ks[2][64 * 64];       // 16 KB
    __shared__ __align__(16) bf16 Vs[2][64 * 64];       // 16 KB

    const int lane = threadIdx.x & 63;
    const int wave = threadIdx.x >> 6;
    const int l16  = lane & 15;
    const int quad = lane >> 4;

    const int hh    = blockIdx.y;
    const int zz    = blockIdx.z;
    const int qbase = blockIdx.x * 256 + wave * 64;
    const int niter = 64 / TS;
    const int tbase = zz * niter;

    const bf16* Qh = Qb + (size_t)hh * SEQ * HEAD_DIM;
    const bf16* Kh = Kb + (size_t)hh * SEQ * HEAD_DIM;
    const bf16* Vh = Vt + (size_t)hh * HEAD_DIM * SEQ;

    const int g0 = wave * 128 + lane, g1 = g0 + 64;
    const int sr0 = g0 >> 3, sc0 = (g0 & 7) ^ (sr0 & 7);
    const int sr1 = g1 >> 3, sc1 = (g1 & 7) ^ (sr1 & 7);

    bf16x8 qf[4][2];
#pragma unroll
    for (int m = 0; m < 4; ++m)
#pragma unroll
        for (int ks = 0; ks < 2; ++ks)
            qf[m][ks] = *(const bf16x8*)(Qh + (size_t)(qbase + m * 16 + l16) * HEAD_DIM
                                         + ks * 32 + quad * 8);

    floatx4 o[4][4] = {};           // o[m][dt] = O^T frag: rows d, cols m
    float ls[4] = {0.f, 0.f, 0.f, 0.f};

    const int swk = l16 & 7;

    auto stage = [&](int slot, int t) {
        async16(&Ks[slot][(wave * 128) * 8],      Kh + (size_t)(t * 64 + sr0) * HEAD_DIM + sc0 * 8);
        async16(&Ks[slot][(wave * 128 + 64) * 8], Kh + (size_t)(t * 64 + sr1) * HEAD_DIM + sc1 * 8);
        async16(&Vs[slot][(wave * 128) * 8],      Vh + (size_t)sr0 * SEQ + t * 64 + sc0 * 8);
        async16(&Vs[slot][(wave * 128 + 64) * 8], Vh + (size_t)sr1 * SEQ + t * 64 + sc1 * 8);
    };

    stage(0, tbase);
    __syncthreads();

    for (int t = 0; t < niter; ++t) {
        const int cur = t & 1;
        if (t + 1 < niter) stage(cur ^ 1, tbase + t + 1);

        // K fragments (A of S^T), b128 swizzled
        bf16x8 kf[4][2];
#pragma unroll
        for (int tt = 0; tt < 4; ++tt)
#pragma unroll
            for (int ks = 0; ks < 2; ++ks)
                kf[tt][ks] = *(const bf16x8*)(&Ks[cur][(size_t)(tt * 16 + l16) * 64
                                              + (((ks * 4 + quad) ^ swk) * 8)]);

        // V^T A-fragments for 16x16x16: lane l16 = d, k = quad*4+j (4 t's, b64)
        bf16x4 vaf[4][4];
#pragma unroll
        for (int dt = 0; dt < 4; ++dt)
#pragma unroll
            for (int c = 0; c < 4; ++c) {
                int row = dt * 16 + l16;
                int boff = row * 128 + (((c * 2 + (quad >> 1)) ^ (row & 7)) * 16)
                         + (quad & 1) * 8;
                vaf[dt][c] = *(const bf16x4*)((const char*)&Vs[cur][0] + boff);
            }

#pragma unroll
        for (int m = 0; m < 4; ++m) {
            bf16x4 pfr[4];
#pragma unroll
            for (int tt = 0; tt < 4; ++tt) {
                floatx4 s = {};
                s = __builtin_amdgcn_mfma_f32_16x16x32_bf16(kf[tt][0], qf[m][0], s, 0, 0, 0);
                s = __builtin_amdgcn_mfma_f32_16x16x32_bf16(kf[tt][1], qf[m][1], s, 0, 0, 0);
                bf16x4 pk;
                float sum = 0.f;
#pragma unroll
                for (int r = 0; r < 4; ++r) {
                    float e = __builtin_amdgcn_exp2f(s[r]);
                    sum += e;
                    pk[r] = (bf16)e;
                }
                ls[m] += sum;
                pfr[tt] = pk;     // == B-operand frag of P^T for t-chunk tt
            }
#pragma unroll
            for (int dt = 0; dt < 4; ++dt)
#pragma unroll
                for (int c = 0; c < 4; ++c)
                    o[m][dt] = mfma16(vaf[dt][c], pfr[c], o[m][dt]);
        }
        __syncthreads();
    }

    // rowsums: reduce across quads (lanes differing in bits 4,5)
#pragma unroll
    for (int m = 0; m < 4; ++m) {
        ls[m] += __shfl_xor(ls[m], 16, 64);
        ls[m] += __shfl_xor(ls[m], 32, 64);
    }

    if (TS == 1) {
#pragma unroll
        for (int m = 0; m < 4; ++m) {
            float inv = 1.0f / ls[m];
            int srow = qbase + m * 16 + l16;
#pragma unroll
            for (int dt = 0; dt < 4; ++dt) {
                float4 r;
                r.x = o[m][dt][0] * inv; r.y = o[m][dt][1] * inv;
                r.z = o[m][dt][2] * inv; r.w = o[m][dt][3] * inv;
                *(float4*)(out + (size_t)srow * (NUM_HEADS * HEAD_DIM)
                           + hh * 64 + dt * 16 + quad * 4) = r;
            }
        }
    } else {
        float* Oz = Op + ((size_t)(zz * NUM_HEADS + hh) * SEQ) * HEAD_DIM;
        float* Lz = Lp + (size_t)(zz * NUM_HEADS + hh) * SEQ;
#pragma unroll
        for (int m = 0; m < 4; ++m) {
            int srow = qbase + m * 16 + l16;
#pragma unroll
            for (int dt = 0; dt < 4; ++dt) {
                float4 r;
                r.x = o[m][dt][0]; r.y = o[m][dt][1];
                r.z = o[m][dt][2]; r.w = o[m][dt][3];
                *(float4*)(Oz + (size_t)srow * HEAD_DIM + dt * 16 + quad * 4) = r;
            }
            if (quad == 0) Lz[srow] = ls[m];
        }
    }
}

template<int NS>
__global__ void mha_combine(const float* __restrict__ Op, const float* __restrict__ Lp,
                            float* __restrict__ out) {
    int i = blockIdx.x * blockDim.x + threadIdx.x;
    int j = i * 4;
    int s = j >> 10, rem = j & 1023, hh = rem >> 6, d = rem & 63;
    const size_t OS = (size_t)NUM_HEADS * SEQ * HEAD_DIM;
    const size_t LS = (size_t)NUM_HEADS * SEQ;
    size_t base = ((size_t)hh * SEQ + s) * HEAD_DIM + d;
    float4 acc = {0.f, 0.f, 0.f, 0.f};
    float l = 0.f;
#pragma unroll
    for (int z = 0; z < NS; ++z) {
        float4 a = *(const float4*)(Op + z * OS + base);
        acc.x += a.x; acc.y += a.y; acc.z += a.z; acc.w += a.w;
        l += Lp[z * LS + (size_t)hh * SEQ + s];
    }
    float inv = 1.0f / l;
    float4 r;
    r.x = acc.x * inv; r.y = acc.y * inv; r.z = acc.z * inv; r.w = acc.w * inv;
    *(float4*)(out + j) = r;
}

extern "C" void kernel_launch(void* const* d_in, const int* in_sizes, int n_in,
                              void* d_out, int out_size, void* d_ws, size_t ws_size,
                              hipStream_t stream) {
    const float* h  = (const float*)d_in[0];
    const float* Wq = (const float*)d_in[1];
    const float* Wk = (const float*)d_in[2];
    const float* Wv = (const float*)d_in[3];
    const float* bq = (const float*)d_in[4];
    const float* bk = (const float*)d_in[5];
    const float* bv = (const float*)d_in[6];
    float* out = (float*)d_out;

    char* ws = (char*)d_ws;
    const size_t MB = 1024 * 1024;
    bf16* Qb = (bf16*)(ws);
    bf16* Kb = (bf16*)(ws + 8 * MB);
    bf16* Vt = (bf16*)(ws + 16 * MB);
    bf16* hb = (bf16*)(ws + 24 * MB);
    bf16* Wt = (bf16*)(ws + 32 * MB);

    const size_t OSZ = (size_t)NUM_HEADS * SEQ * HEAD_DIM * 4;   // 16.78 MB / slice
    const size_t LSZ = (size_t)NUM_HEADS * SEQ * 4;              // 0.26 MB / slice
    float* Op = (float*)(ws + 24 * MB);                          // overlays dead hb/Wt

    mha_conv_h<<<(SEQ * IN_DIM / 4) / 256, 256, 0, stream>>>(h, hb);
    mha_conv_wt<<<dim3(16, 16, 3), 256, 0, stream>>>(Wq, Wk, Wv, Wt);
    mha_qkv_gemm<<<dim3(SEQ / 128, (3 * IN_DIM) / 128), 256, 0, stream>>>(
        hb, Wt, bq, bk, bv, Qb, Kb, Vt);

    if (ws_size >= 24 * MB + 4 * (OSZ + LSZ)) {
        float* Lp = (float*)(ws + 24 * MB + 4 * OSZ);
        mha_attn<4><<<dim3(SEQ / 256, NUM_HEADS, 4), 256, 0, stream>>>(
            Qb, Kb, Vt, Op, Lp, out);
        mha_combine<4><<<(SEQ * IN_DIM / 4) / 256, 256, 0, stream>>>(Op, Lp, out);
    } else if (ws_size >= 24 * MB + 2 * (OSZ + LSZ)) {
        float* Lp = (float*)(ws + 24 * MB + 2 * OSZ);
        mha_attn<2><<<dim3(SEQ / 256, NUM_HEADS, 2), 256, 0, stream>>>(
            Qb, Kb, Vt, Op, Lp, out);
        mha_combine<2><<<(SEQ * IN_DIM / 4) / 256, 256, 0, stream>>>(Op, Lp, out);
    } else {
        mha_attn<1><<<dim3(SEQ / 256, NUM_HEADS, 1), 256, 0, stream>>>(
            Qb, Kb, Vt, nullptr, nullptr, out);
    }
}